// Round 6
// baseline (233.264 us; speedup 1.0000x reference)
//
#include <hip/hip_runtime.h>
#include <stdint.h>

// GradientLoss: sum_c mean( (conv3d_c(x) - conv3d_c(y))^2 ), c in {d,h,w} Sobel dirs.
// conv linear -> conv(x)-conv(y) = conv(x-y). Separable: s=[1,2,1], g=[1,0,-1];
// SAME zero pad; squared output -> flip irrelevant.
//
// R15 = R14 (pure-register streaming, RW=4) + DEPTH-2 PREFETCH.
//  - Model from R13/R14 counters: delivered-to-CU BW follows Little's law,
//    delivered ~ bytes-in-flight/CU with ceiling ~6.3-6.5 TB/s (fill kernel).
//      R13: 96 KB in flight -> 5.9 TB/s (264 MB demand -> 44.8us)
//      R14: 72 KB in flight -> 4.2 TB/s (198 MB demand -> 46.9us)
//    R14's demand cut was cancelled by lost in-flight (waves fixed at
//    N*(D/TD)*(H/RW) = 1536 = 6/CU).
//  - Fix: second XR buffer -> 2 planes (24 KB) in flight per wave;
//    144 KB/CU > R13's 96 KB -> delivered should hit the cap on 198 MB
//    demand -> predicted ~31-33us.
//  - Manual 2x loop unroll with NAMED buffers XRa/XRb (runtime-indexed
//    register arrays spill to scratch). Loads: exactly 12 batches/wave,
//    issued at iter it for consumption at it+2 (2-iter slack).
//  - launch_bounds(128,2): VGPR cap 256 (est ~180, R12 lesson: verify
//    WRITE_SIZE stays KB = no spill).

#define N_  2
#define D_  160
#define H_  192
#define W_  224
#define PS  (H_ * W_)

#define TD  10                 // d-planes per block (160/10 = 16 chunks)
#define RW  4                  // output rows per wave
#define TH  8                  // rows per block = 2 waves x RW
constexpr float SCALE = 1.0f / ((float)N_ * D_ * H_ * W_);

__device__ __forceinline__ float4 f4add(float4 a, float4 b) {
    return make_float4(a.x + b.x, a.y + b.y, a.z + b.z, a.w + b.w);
}
__device__ __forceinline__ float4 f4sub(float4 a, float4 b) {
    return make_float4(a.x - b.x, a.y - b.y, a.z - b.z, a.w - b.w);
}
__device__ __forceinline__ float4 f4fma(float k, float4 a, float4 b) {  // k*a + b
    return make_float4(fmaf(k, a.x, b.x), fmaf(k, a.y, b.y),
                       fmaf(k, a.z, b.z), fmaf(k, a.w, b.w));
}

__global__ __launch_bounds__(128, 2)
void grad_loss_kernel(const float* __restrict__ x, const float* __restrict__ y,
                      float* __restrict__ out) {
    __shared__ float wsum[2];

    const int tid  = threadIdx.x;
    const int lane = tid & 63;
    const int wv   = tid >> 6;                 // 0..1

    const int nchunks = D_ / TD;               // 16
    const int nb = blockIdx.z / nchunks;
    const int d0 = (blockIdx.z % nchunks) * TD;
    const int h0w = blockIdx.y * TH + RW * wv; // this wave's first output row

    const float* vbx = x + (size_t)nb * ((size_t)D_ * PS);
    const float* vby = y + (size_t)nb * ((size_t)D_ * PS);

    // Per-lane row offsets (clamped) + masks. Lanes 56..63 duplicate lane 55's
    // 16B (same cache line, valid memory) and are zeroed by the mask.
    const bool wact = lane < 56;               // 56 lanes x 4 floats = 224 = W
    const int lo4c = (lane < 56 ? lane : 55) * 4;
    int off[6];
    float rmask[6];
    #pragma unroll
    for (int r = 0; r < 6; ++r) {              // loaded rows h0w-1 .. h0w+4
        int gh  = h0w - 1 + r;
        int ghc = min(max(gh, 0), H_ - 1);
        off[r]   = ghc * W_ + lo4c;
        rmask[r] = (((unsigned)gh < (unsigned)H_) && wact) ? 1.f : 0.f;
    }

    float4 XRa[12], XRb[12];                   // 2 planes in flight: 6 rows x {x,y}
    auto loadp = [&](int p, float4* XR) {
        int pc = min(max(p, 0), D_ - 1);       // clamp; masked via pm on use
        const float* bx = vbx + (size_t)pc * PS;
        const float* by = vby + (size_t)pc * PS;
        #pragma unroll
        for (int r = 0; r < 6; ++r) {
            XR[2 * r]     = *(const float4*)(bx + off[r]);
            XR[2 * r + 1] = *(const float4*)(by + off[r]);
        }
    };

    float4 A0[RW], A1[RW], A2[RW], B0[RW], B1[RW], B2[RW];  // d-hist (q-2,q-1)
    const float4 z4 = make_float4(0.f, 0.f, 0.f, 0.f);
    #pragma unroll
    for (int j = 0; j < RW; ++j) { A0[j]=A1[j]=A2[j]=B0[j]=B1[j]=B2[j]=z4; }
    float acc = 0.f;

    // ---- body for one iteration; XR = buffer holding plane q = d0-1+it ----
    auto body = [&](int it, float4* XR) {
        const int q = d0 - 1 + it;             // plane whose stencil we compute
        const float pm = (q >= 0 && q < D_) ? 1.f : 0.f;

        // consume XR row-by-row into n accumulators (waits on this batch only;
        // the other buffer's batch stays in flight)
        float4 n0[RW], n1[RW], n2[RW];
        #pragma unroll
        for (int r = 0; r < 6; ++r) {
            const float m = rmask[r] * pm;
            const float4 vv = make_float4((XR[2*r].x - XR[2*r+1].x) * m,
                                          (XR[2*r].y - XR[2*r+1].y) * m,
                                          (XR[2*r].z - XR[2*r+1].z) * m,
                                          (XR[2*r].w - XR[2*r+1].w) * m);
            float Lm = __shfl_up(vv.w, 1, 64);
            float Rp = __shfl_down(vv.x, 1, 64);
            if (lane == 0) Lm = 0.f;           // w = -1 zero pad
            // lane 55's Rp comes from lane 56: vv there is 0 (mask) ✓
            const float4 s = make_float4(Lm + 2.f * vv.x + vv.y,
                                         vv.x + 2.f * vv.y + vv.z,
                                         vv.y + 2.f * vv.z + vv.w,
                                         vv.z + 2.f * vv.w + Rp);
            const float4 g = make_float4(Lm - vv.y, vv.x - vv.z,
                                         vv.y - vv.w, vv.z - Rp);
            #pragma unroll
            for (int j = 0; j < RW; ++j) {
                if (r == j) {                  // top row of output j
                    n0[j] = s; n1[j] = s; n2[j] = g;
                } else if (r == j + 1) {       // center row, weight 2 (s only)
                    n0[j] = f4fma(2.f, s, n0[j]);
                    n2[j] = f4fma(2.f, g, n2[j]);
                } else if (r == j + 2) {       // bottom row
                    n0[j] = f4add(n0[j], s);
                    n1[j] = f4sub(n1[j], s);
                    n2[j] = f4add(n2[j], g);
                }
            }
        }

        // refill THIS buffer with plane d0+1+it (consumed at iter it+2)
        if (it < TD) loadp(d0 + 1 + it, XR);

        // d-combine for center plane q-1 (A = q-2, B = q-1, n = q)
        if (it >= 2 && wact) {
            #pragma unroll
            for (int j = 0; j < RW; ++j) {
                const float4 gx = f4sub(A0[j], n0[j]);                    // g_d s_h s_w
                const float4 gy = f4add(f4fma(2.f, B1[j], A1[j]), n1[j]); // s_d g_h s_w
                const float4 gz = f4add(f4fma(2.f, B2[j], A2[j]), n2[j]); // s_d s_h g_w
                acc = fmaf(gx.x, gx.x, acc); acc = fmaf(gx.y, gx.y, acc);
                acc = fmaf(gx.z, gx.z, acc); acc = fmaf(gx.w, gx.w, acc);
                acc = fmaf(gy.x, gy.x, acc); acc = fmaf(gy.y, gy.y, acc);
                acc = fmaf(gy.z, gy.z, acc); acc = fmaf(gy.w, gy.w, acc);
                acc = fmaf(gz.x, gz.x, acc); acc = fmaf(gz.y, gz.y, acc);
                acc = fmaf(gz.z, gz.z, acc); acc = fmaf(gz.w, gz.w, acc);
            }
        }

        // rotate history
        #pragma unroll
        for (int j = 0; j < RW; ++j) {
            A0[j] = B0[j]; A1[j] = B1[j]; A2[j] = B2[j];
            B0[j] = n0[j]; B1[j] = n1[j]; B2[j] = n2[j];
        }
    };

    // ---- prologue: planes d0-1, d0 in flight (2 batches) ----
    loadp(d0 - 1, XRa);
    loadp(d0,     XRb);

    // TD+2 = 12 iterations, manually unrolled x2 for static buffer selection
    #pragma unroll 1
    for (int i2 = 0; i2 < (TD + 2) / 2; ++i2) {
        body(2 * i2,     XRa);
        body(2 * i2 + 1, XRb);
    }

    // ---- reduction: wave butterfly, LDS combine, one atomic per block ----
    #pragma unroll
    for (int off_ = 32; off_ > 0; off_ >>= 1)
        acc += __shfl_xor(acc, off_, 64);
    if (lane == 0) wsum[wv] = acc;
    __syncthreads();
    if (tid == 0) {
        atomicAdd(out, (wsum[0] + wsum[1]) * SCALE);
    }
}

extern "C" void kernel_launch(void* const* d_in, const int* in_sizes, int n_in,
                              void* d_out, int out_size, void* d_ws, size_t ws_size,
                              hipStream_t stream) {
    const float* x = (const float*)d_in[0];
    const float* y = (const float*)d_in[1];
    float* out = (float*)d_out;

    hipMemsetAsync(out, 0, sizeof(float), stream);

    dim3 block(128);                    // 2 independent waves; no intra-loop sync
    dim3 grid(1,
              H_ / TH,                  // 24
              N_ * (D_ / TD));          // 32  -> 768 blocks
    grad_loss_kernel<<<grid, block, 0, stream>>>(x, y, out);
}

// Round 7
// 232.898 us; speedup vs baseline: 1.0016x; 1.0016x over previous
//
#include <hip/hip_runtime.h>
#include <stdint.h>

// GradientLoss: sum_c mean( (conv3d_c(x) - conv3d_c(y))^2 ), c in {d,h,w} Sobel dirs.
// conv linear -> conv(x)-conv(y) = conv(x-y). Separable: s=[1,2,1], g=[1,0,-1];
// SAME zero pad; squared output -> flip irrelevant.
//
// R16 = R15 (RW=4, depth-2 prefetch) with MACRO bodies — fix the spill.
//  - R15 post-mortem: lambda took float4* XR -> address-taken arrays defeated
//    SROA -> XRa/XRb allocated in SCRATCH (WRITE_SIZE 201 MB, VGPR=128 with
//    arrays in memory, 143us). The depth-2 experiment never ran.
//  - Fix: LOADP/BODY are macros whose buffer argument is the NAME XRa/XRb;
//    after unrolling every access is a static index on a named local array ->
//    promotable. Predicted real VGPR ~160-190 (R13/R14 show allocator
//    coalesces hist/n at ~0.6x naive count) < 256 cap at launch_bounds(128,2).
//  - Model under test (R13/R14 counters): delivered-to-CU BW ~ Little's law;
//    R13: 96 KB in-flight/CU -> 5.9 TB/s; R14: 72 KB -> 4.2 TB/s; ceiling
//    ~6.5 TB/s (harness fill kernel). R16: 6 waves/CU x 24 KB = 144 KB on
//    198 MB demand (1.5x h-halo * 1.2x d-halo) -> predicted 31-36us.

#define N_  2
#define D_  160
#define H_  192
#define W_  224
#define PS  (H_ * W_)

#define TD  10                 // d-planes per block (160/10 = 16 chunks)
#define RW  4                  // output rows per wave
#define TH  8                  // rows per block = 2 waves x RW
constexpr float SCALE = 1.0f / ((float)N_ * D_ * H_ * W_);

__device__ __forceinline__ float4 f4add(float4 a, float4 b) {
    return make_float4(a.x + b.x, a.y + b.y, a.z + b.z, a.w + b.w);
}
__device__ __forceinline__ float4 f4sub(float4 a, float4 b) {
    return make_float4(a.x - b.x, a.y - b.y, a.z - b.z, a.w - b.w);
}
__device__ __forceinline__ float4 f4fma(float k, float4 a, float4 b) {  // k*a + b
    return make_float4(fmaf(k, a.x, b.x), fmaf(k, a.y, b.y),
                       fmaf(k, a.z, b.z), fmaf(k, a.w, b.w));
}

// ---- macros: buffer argument is a NAME (XRa/XRb); all indices static ----
#define LOADP(p, XR) do {                                                      \
    int pc_ = min(max((p), 0), D_ - 1);        /* clamp; masked via pm */      \
    const float* bx_ = vbx + (size_t)pc_ * PS;                                 \
    const float* by_ = vby + (size_t)pc_ * PS;                                 \
    _Pragma("unroll")                                                          \
    for (int r_ = 0; r_ < 6; ++r_) {                                           \
        XR[2 * r_]     = *(const float4*)(bx_ + off[r_]);                      \
        XR[2 * r_ + 1] = *(const float4*)(by_ + off[r_]);                      \
    }                                                                          \
} while (0)

#define BODY(ITV, XR) do {                                                     \
    const int it_ = (ITV);                                                     \
    const int q_ = d0 - 1 + it_;               /* plane consumed this iter */  \
    const float pm_ = (q_ >= 0 && q_ < D_) ? 1.f : 0.f;                        \
    float4 n0[RW], n1[RW], n2[RW];                                             \
    _Pragma("unroll")                                                          \
    for (int r_ = 0; r_ < 6; ++r_) {                                           \
        const float m_ = rmask[r_] * pm_;                                      \
        const float4 vv = make_float4((XR[2*r_].x - XR[2*r_+1].x) * m_,        \
                                      (XR[2*r_].y - XR[2*r_+1].y) * m_,        \
                                      (XR[2*r_].z - XR[2*r_+1].z) * m_,        \
                                      (XR[2*r_].w - XR[2*r_+1].w) * m_);       \
        float Lm = __shfl_up(vv.w, 1, 64);                                     \
        float Rp = __shfl_down(vv.x, 1, 64);                                   \
        if (lane == 0) Lm = 0.f;               /* w = -1 zero pad */           \
        /* lane 55's Rp comes from lane 56: vv there is 0 (mask) */            \
        const float4 s_ = make_float4(Lm + 2.f * vv.x + vv.y,                  \
                                      vv.x + 2.f * vv.y + vv.z,                \
                                      vv.y + 2.f * vv.z + vv.w,                \
                                      vv.z + 2.f * vv.w + Rp);                 \
        const float4 g_ = make_float4(Lm - vv.y, vv.x - vv.z,                  \
                                      vv.y - vv.w, vv.z - Rp);                 \
        _Pragma("unroll")                                                      \
        for (int j_ = 0; j_ < RW; ++j_) {                                      \
            if (r_ == j_) {                    /* top row of output j */       \
                n0[j_] = s_; n1[j_] = s_; n2[j_] = g_;                         \
            } else if (r_ == j_ + 1) {         /* center row, weight 2 */      \
                n0[j_] = f4fma(2.f, s_, n0[j_]);                               \
                n2[j_] = f4fma(2.f, g_, n2[j_]);                               \
            } else if (r_ == j_ + 2) {         /* bottom row */                \
                n0[j_] = f4add(n0[j_], s_);                                    \
                n1[j_] = f4sub(n1[j_], s_);                                    \
                n2[j_] = f4add(n2[j_], g_);                                    \
            }                                                                  \
        }                                                                      \
    }                                                                          \
    /* refill THIS buffer with plane d0+1+it (consumed at iter it+2) */        \
    if (it_ < TD) LOADP(d0 + 1 + it_, XR);                                     \
    /* d-combine for center plane q-1 (A = q-2, B = q-1, n = q) */             \
    if (it_ >= 2 && wact) {                                                    \
        _Pragma("unroll")                                                      \
        for (int j_ = 0; j_ < RW; ++j_) {                                      \
            const float4 gx = f4sub(A0[j_], n0[j_]);                           \
            const float4 gy = f4add(f4fma(2.f, B1[j_], A1[j_]), n1[j_]);       \
            const float4 gz = f4add(f4fma(2.f, B2[j_], A2[j_]), n2[j_]);       \
            acc = fmaf(gx.x, gx.x, acc); acc = fmaf(gx.y, gx.y, acc);          \
            acc = fmaf(gx.z, gx.z, acc); acc = fmaf(gx.w, gx.w, acc);          \
            acc = fmaf(gy.x, gy.x, acc); acc = fmaf(gy.y, gy.y, acc);          \
            acc = fmaf(gy.z, gy.z, acc); acc = fmaf(gy.w, gy.w, acc);          \
            acc = fmaf(gz.x, gz.x, acc); acc = fmaf(gz.y, gz.y, acc);          \
            acc = fmaf(gz.z, gz.z, acc); acc = fmaf(gz.w, gz.w, acc);          \
        }                                                                      \
    }                                                                          \
    /* rotate history */                                                       \
    _Pragma("unroll")                                                          \
    for (int j_ = 0; j_ < RW; ++j_) {                                          \
        A0[j_] = B0[j_]; A1[j_] = B1[j_]; A2[j_] = B2[j_];                     \
        B0[j_] = n0[j_]; B1[j_] = n1[j_]; B2[j_] = n2[j_];                     \
    }                                                                          \
} while (0)

__global__ __launch_bounds__(128, 2)
void grad_loss_kernel(const float* __restrict__ x, const float* __restrict__ y,
                      float* __restrict__ out) {
    __shared__ float wsum[2];

    const int tid  = threadIdx.x;
    const int lane = tid & 63;
    const int wv   = tid >> 6;                 // 0..1

    const int nchunks = D_ / TD;               // 16
    const int nb = blockIdx.z / nchunks;
    const int d0 = (blockIdx.z % nchunks) * TD;
    const int h0w = blockIdx.y * TH + RW * wv; // this wave's first output row

    const float* vbx = x + (size_t)nb * ((size_t)D_ * PS);
    const float* vby = y + (size_t)nb * ((size_t)D_ * PS);

    // Per-lane row offsets (clamped) + masks. Lanes 56..63 duplicate lane 55's
    // 16B (same cache line, valid memory) and are zeroed by the mask.
    const bool wact = lane < 56;               // 56 lanes x 4 floats = 224 = W
    const int lo4c = (lane < 56 ? lane : 55) * 4;
    int off[6];
    float rmask[6];
    #pragma unroll
    for (int r = 0; r < 6; ++r) {              // loaded rows h0w-1 .. h0w+4
        int gh  = h0w - 1 + r;
        int ghc = min(max(gh, 0), H_ - 1);
        off[r]   = ghc * W_ + lo4c;
        rmask[r] = (((unsigned)gh < (unsigned)H_) && wact) ? 1.f : 0.f;
    }

    float4 XRa[12], XRb[12];                   // 2 planes in flight: 6 rows x {x,y}

    float4 A0[RW], A1[RW], A2[RW], B0[RW], B1[RW], B2[RW];  // d-hist (q-2,q-1)
    const float4 z4 = make_float4(0.f, 0.f, 0.f, 0.f);
    #pragma unroll
    for (int j = 0; j < RW; ++j) { A0[j]=A1[j]=A2[j]=B0[j]=B1[j]=B2[j]=z4; }
    float acc = 0.f;

    // ---- prologue: planes d0-1, d0 in flight (2 batches, 24 KB/wave) ----
    LOADP(d0 - 1, XRa);
    LOADP(d0,     XRb);

    // TD+2 = 12 iterations, manually unrolled x2 for static buffer selection
    #pragma unroll 1
    for (int i2 = 0; i2 < (TD + 2) / 2; ++i2) {
        BODY(2 * i2,     XRa);
        BODY(2 * i2 + 1, XRb);
    }

    // ---- reduction: wave butterfly, LDS combine, one atomic per block ----
    #pragma unroll
    for (int off_ = 32; off_ > 0; off_ >>= 1)
        acc += __shfl_xor(acc, off_, 64);
    if (lane == 0) wsum[wv] = acc;
    __syncthreads();
    if (tid == 0) {
        atomicAdd(out, (wsum[0] + wsum[1]) * SCALE);
    }
}

extern "C" void kernel_launch(void* const* d_in, const int* in_sizes, int n_in,
                              void* d_out, int out_size, void* d_ws, size_t ws_size,
                              hipStream_t stream) {
    const float* x = (const float*)d_in[0];
    const float* y = (const float*)d_in[1];
    float* out = (float*)d_out;

    hipMemsetAsync(out, 0, sizeof(float), stream);

    dim3 block(128);                    // 2 independent waves; no intra-loop sync
    dim3 grid(1,
              H_ / TH,                  // 24
              N_ * (D_ / TD));          // 32  -> 768 blocks
    grad_loss_kernel<<<grid, block, 0, stream>>>(x, y, out);
}

// Round 8
// 136.658 us; speedup vs baseline: 1.7069x; 1.7042x over previous
//
#include <hip/hip_runtime.h>
#include <stdint.h>

// GradientLoss: sum_c mean( (conv3d_c(x) - conv3d_c(y))^2 ), c in {d,h,w} Sobel dirs.
// conv linear -> conv(x)-conv(y) = conv(x-y). Separable: s=[1,2,1], g=[1,0,-1];
// SAME zero pad; squared output -> flip irrelevant.
//
// R17 = R16 (RW=4, depth-2 prefetch, macro bodies) with launch_bounds(128,1).
//  - R16 post-mortem: STILL spilled (WRITE 199MB) at VGPR_Count = exactly 128,
//    despite SROA-clean static indexing. Cross-round evidence: (256,4)->64,
//    (128,2)->128 => effective VGPR cap = 256/arg2 on this toolchain. The cap,
//    not SROA, forced the spill; R14 fit at exactly 128 (no spill) confirms.
//  - Fix: arg2=1 -> cap 256. Est. need ~170-200. Occupancy is grid-limited at
//    6 waves/CU (768 blocks x 2 waves / 256 CU) either way; at ~190 VGPR the
//    HW still permits 2 waves/SIMD > the 1.5 avg the grid supplies.
//  - Model under test (unchanged, still never executed in-registers):
//    delivered-to-CU BW ~ bytes-in-flight (Little's law), ceiling ~6.5 TB/s
//    (harness fill kernel). R13: 96 KB/CU -> 5.9 TB/s on 264 MB demand ->
//    44.8us. R17: 144 KB/CU on 198 MB demand (1.5x h-halo * 1.2x d-halo)
//    -> predicted 31-36us. Falsifier: no-spill + ~45us kills the model.

#define N_  2
#define D_  160
#define H_  192
#define W_  224
#define PS  (H_ * W_)

#define TD  10                 // d-planes per block (160/10 = 16 chunks)
#define RW  4                  // output rows per wave
#define TH  8                  // rows per block = 2 waves x RW
constexpr float SCALE = 1.0f / ((float)N_ * D_ * H_ * W_);

__device__ __forceinline__ float4 f4add(float4 a, float4 b) {
    return make_float4(a.x + b.x, a.y + b.y, a.z + b.z, a.w + b.w);
}
__device__ __forceinline__ float4 f4sub(float4 a, float4 b) {
    return make_float4(a.x - b.x, a.y - b.y, a.z - b.z, a.w - b.w);
}
__device__ __forceinline__ float4 f4fma(float k, float4 a, float4 b) {  // k*a + b
    return make_float4(fmaf(k, a.x, b.x), fmaf(k, a.y, b.y),
                       fmaf(k, a.z, b.z), fmaf(k, a.w, b.w));
}

// ---- macros: buffer argument is a NAME (XRa/XRb); all indices static ----
#define LOADP(p, XR) do {                                                      \
    int pc_ = min(max((p), 0), D_ - 1);        /* clamp; masked via pm */      \
    const float* bx_ = vbx + (size_t)pc_ * PS;                                 \
    const float* by_ = vby + (size_t)pc_ * PS;                                 \
    _Pragma("unroll")                                                          \
    for (int r_ = 0; r_ < 6; ++r_) {                                           \
        XR[2 * r_]     = *(const float4*)(bx_ + off[r_]);                      \
        XR[2 * r_ + 1] = *(const float4*)(by_ + off[r_]);                      \
    }                                                                          \
} while (0)

#define BODY(ITV, XR) do {                                                     \
    const int it_ = (ITV);                                                     \
    const int q_ = d0 - 1 + it_;               /* plane consumed this iter */  \
    const float pm_ = (q_ >= 0 && q_ < D_) ? 1.f : 0.f;                        \
    float4 n0[RW], n1[RW], n2[RW];                                             \
    _Pragma("unroll")                                                          \
    for (int r_ = 0; r_ < 6; ++r_) {                                           \
        const float m_ = rmask[r_] * pm_;                                      \
        const float4 vv = make_float4((XR[2*r_].x - XR[2*r_+1].x) * m_,        \
                                      (XR[2*r_].y - XR[2*r_+1].y) * m_,        \
                                      (XR[2*r_].z - XR[2*r_+1].z) * m_,        \
                                      (XR[2*r_].w - XR[2*r_+1].w) * m_);       \
        float Lm = __shfl_up(vv.w, 1, 64);                                     \
        float Rp = __shfl_down(vv.x, 1, 64);                                   \
        if (lane == 0) Lm = 0.f;               /* w = -1 zero pad */           \
        /* lane 55's Rp comes from lane 56: vv there is 0 (mask) */            \
        const float4 s_ = make_float4(Lm + 2.f * vv.x + vv.y,                  \
                                      vv.x + 2.f * vv.y + vv.z,                \
                                      vv.y + 2.f * vv.z + vv.w,                \
                                      vv.z + 2.f * vv.w + Rp);                 \
        const float4 g_ = make_float4(Lm - vv.y, vv.x - vv.z,                  \
                                      vv.y - vv.w, vv.z - Rp);                 \
        _Pragma("unroll")                                                      \
        for (int j_ = 0; j_ < RW; ++j_) {                                      \
            if (r_ == j_) {                    /* top row of output j */       \
                n0[j_] = s_; n1[j_] = s_; n2[j_] = g_;                         \
            } else if (r_ == j_ + 1) {         /* center row, weight 2 */      \
                n0[j_] = f4fma(2.f, s_, n0[j_]);                               \
                n2[j_] = f4fma(2.f, g_, n2[j_]);                               \
            } else if (r_ == j_ + 2) {         /* bottom row */                \
                n0[j_] = f4add(n0[j_], s_);                                    \
                n1[j_] = f4sub(n1[j_], s_);                                    \
                n2[j_] = f4add(n2[j_], g_);                                    \
            }                                                                  \
        }                                                                      \
    }                                                                          \
    /* refill THIS buffer with plane d0+1+it (consumed at iter it+2) */        \
    if (it_ < TD) LOADP(d0 + 1 + it_, XR);                                     \
    /* d-combine for center plane q-1 (A = q-2, B = q-1, n = q) */             \
    if (it_ >= 2 && wact) {                                                    \
        _Pragma("unroll")                                                      \
        for (int j_ = 0; j_ < RW; ++j_) {                                      \
            const float4 gx = f4sub(A0[j_], n0[j_]);                           \
            const float4 gy = f4add(f4fma(2.f, B1[j_], A1[j_]), n1[j_]);       \
            const float4 gz = f4add(f4fma(2.f, B2[j_], A2[j_]), n2[j_]);       \
            acc = fmaf(gx.x, gx.x, acc); acc = fmaf(gx.y, gx.y, acc);          \
            acc = fmaf(gx.z, gx.z, acc); acc = fmaf(gx.w, gx.w, acc);          \
            acc = fmaf(gy.x, gy.x, acc); acc = fmaf(gy.y, gy.y, acc);          \
            acc = fmaf(gy.z, gy.z, acc); acc = fmaf(gy.w, gy.w, acc);          \
            acc = fmaf(gz.x, gz.x, acc); acc = fmaf(gz.y, gz.y, acc);          \
            acc = fmaf(gz.z, gz.z, acc); acc = fmaf(gz.w, gz.w, acc);          \
        }                                                                      \
    }                                                                          \
    /* rotate history */                                                       \
    _Pragma("unroll")                                                          \
    for (int j_ = 0; j_ < RW; ++j_) {                                          \
        A0[j_] = B0[j_]; A1[j_] = B1[j_]; A2[j_] = B2[j_];                     \
        B0[j_] = n0[j_]; B1[j_] = n1[j_]; B2[j_] = n2[j_];                     \
    }                                                                          \
} while (0)

__global__ __launch_bounds__(128, 1)
void grad_loss_kernel(const float* __restrict__ x, const float* __restrict__ y,
                      float* __restrict__ out) {
    __shared__ float wsum[2];

    const int tid  = threadIdx.x;
    const int lane = tid & 63;
    const int wv   = tid >> 6;                 // 0..1

    const int nchunks = D_ / TD;               // 16
    const int nb = blockIdx.z / nchunks;
    const int d0 = (blockIdx.z % nchunks) * TD;
    const int h0w = blockIdx.y * TH + RW * wv; // this wave's first output row

    const float* vbx = x + (size_t)nb * ((size_t)D_ * PS);
    const float* vby = y + (size_t)nb * ((size_t)D_ * PS);

    // Per-lane row offsets (clamped) + masks. Lanes 56..63 duplicate lane 55's
    // 16B (same cache line, valid memory) and are zeroed by the mask.
    const bool wact = lane < 56;               // 56 lanes x 4 floats = 224 = W
    const int lo4c = (lane < 56 ? lane : 55) * 4;
    int off[6];
    float rmask[6];
    #pragma unroll
    for (int r = 0; r < 6; ++r) {              // loaded rows h0w-1 .. h0w+4
        int gh  = h0w - 1 + r;
        int ghc = min(max(gh, 0), H_ - 1);
        off[r]   = ghc * W_ + lo4c;
        rmask[r] = (((unsigned)gh < (unsigned)H_) && wact) ? 1.f : 0.f;
    }

    float4 XRa[12], XRb[12];                   // 2 planes in flight: 6 rows x {x,y}

    float4 A0[RW], A1[RW], A2[RW], B0[RW], B1[RW], B2[RW];  // d-hist (q-2,q-1)
    const float4 z4 = make_float4(0.f, 0.f, 0.f, 0.f);
    #pragma unroll
    for (int j = 0; j < RW; ++j) { A0[j]=A1[j]=A2[j]=B0[j]=B1[j]=B2[j]=z4; }
    float acc = 0.f;

    // ---- prologue: planes d0-1, d0 in flight (2 batches, 24 KB/wave) ----
    LOADP(d0 - 1, XRa);
    LOADP(d0,     XRb);

    // TD+2 = 12 iterations, manually unrolled x2 for static buffer selection
    #pragma unroll 1
    for (int i2 = 0; i2 < (TD + 2) / 2; ++i2) {
        BODY(2 * i2,     XRa);
        BODY(2 * i2 + 1, XRb);
    }

    // ---- reduction: wave butterfly, LDS combine, one atomic per block ----
    #pragma unroll
    for (int off_ = 32; off_ > 0; off_ >>= 1)
        acc += __shfl_xor(acc, off_, 64);
    if (lane == 0) wsum[wv] = acc;
    __syncthreads();
    if (tid == 0) {
        atomicAdd(out, (wsum[0] + wsum[1]) * SCALE);
    }
}

extern "C" void kernel_launch(void* const* d_in, const int* in_sizes, int n_in,
                              void* d_out, int out_size, void* d_ws, size_t ws_size,
                              hipStream_t stream) {
    const float* x = (const float*)d_in[0];
    const float* y = (const float*)d_in[1];
    float* out = (float*)d_out;

    hipMemsetAsync(out, 0, sizeof(float), stream);

    dim3 block(128);                    // 2 independent waves; no intra-loop sync
    dim3 grid(1,
              H_ / TH,                  // 24
              N_ * (D_ / TD));          // 32  -> 768 blocks
    grad_loss_kernel<<<grid, block, 0, stream>>>(x, y, out);
}